// Round 7
// baseline (717.843 us; speedup 1.0000x reference)
//
#include <hip/hip_runtime.h>
#include <math.h>

#define B_   16
#define S_   4096
#define I_   128
#define HD_  384
#define M_   256
#define K_   384   // M_+I_
#define EPS_ 1e-5f

// ---------------------------------------------------------------- K1: u_pre + BN(u)
__global__ __launch_bounds__(256) void k_upre(const float* __restrict__ x,
                                              const float* __restrict__ wu,
                                              const float* __restrict__ wub,
                                              const float* __restrict__ g_u,
                                              const float* __restrict__ b_u,
                                              const float* __restrict__ mu_u,
                                              const float* __restrict__ var_u,
                                              float* __restrict__ u_bn) {
    __shared__ float w[I_];
    int tid = threadIdx.x;
    if (tid < I_) w[tid] = wu[tid];
    __syncthreads();
    int row = blockIdx.x * 256 + tid;            // 0..65535
    const float4* xr = (const float4*)(x + (size_t)row * I_);
    const float4* w4 = (const float4*)w;
    float4 s4 = {0.f, 0.f, 0.f, 0.f};
    #pragma unroll
    for (int i = 0; i < I_ / 4; i++) {
        float4 xv = xr[i], wv = w4[i];
        s4.x += xv.x * wv.x; s4.y += xv.y * wv.y;
        s4.z += xv.z * wv.z; s4.w += xv.w * wv.w;
    }
    float s = (s4.x + s4.y) + (s4.z + s4.w) + wub[0];
    float rs = 1.0f / sqrtf(var_u[0] + EPS_);
    u_bn[row] = g_u[0] * (s - mu_u[0]) * rs + b_u[0];
}

// ---------------------------------------------------------------- K2: u-LIF (chunk 4, warm-up 128)
__global__ __launch_bounds__(256) void k_ulif(const float* __restrict__ u_bn,
                                              float* __restrict__ u_spk) {
    int b = blockIdx.x, tid = threadIdx.x;
    int chunk = blockIdx.y * 256 + tid;          // 0..1023
    int t0 = chunk * 4;
    int start = t0 - 128; if (start < 0) start = 0;
    const float* ub = u_bn + (size_t)b * S_;
    float v = 0.f;
    for (int t = start; t < t0 + 4; t++) {
        float xv = ub[t];
        v = v + (xv - v) * 0.5f;
        float sp = (v - 1.0f) >= 0.0f ? 1.0f : 0.0f;
        if (t >= t0) u_spk[(size_t)b * S_ + t] = sp;
        v = v * (1.0f - sp);
    }
}

// ---------------------------------------------------------------- K2b: compact sorted spike lists
__global__ __launch_bounds__(256) void k_compact(const float* __restrict__ u_spk,
                                                 int* __restrict__ spk_idx,
                                                 int* __restrict__ spk_cnt) {
    __shared__ int wcnt[4];
    __shared__ int base;
    int b = blockIdx.x, tid = threadIdx.x;
    int lane = tid & 63, w = tid >> 6;
    if (tid == 0) base = 0;
    __syncthreads();
    for (int r = 0; r < 16; r++) {
        int t = r * 256 + tid;
        bool f = u_spk[(size_t)b * S_ + t] > 0.5f;
        unsigned long long bal = __ballot(f);
        int pre = __popcll(bal & (((unsigned long long)1 << lane) - 1ull));
        if (lane == 0) wcnt[w] = __popcll(bal);
        __syncthreads();
        int off = base;
        for (int i = 0; i < w; i++) off += wcnt[i];
        if (f) spk_idx[(size_t)b * S_ + off + pre] = t;
        __syncthreads();
        if (tid == 0) base += wcnt[0] + wcnt[1] + wcnt[2] + wcnt[3];
        __syncthreads();
    }
    if (tid == 0) spk_cnt[b] = base;
}

// ---------------------------------------------------------------- K3: sparse conv + BN(m) -> m_bn [B,M,S]
// Stride-1 lane mapping (t = tid + 256*i, 16 groups): conflict-free LDS.
// Sorted spike list partitioned into 8 tau-segments; segment g touches exactly
// pairs k>=g -> zero per-spike branches. 512-float zero pad absorbs negative
// in-pair lags. LDS 18.5 KB -> 8 blocks/CU.
template<int G>
__device__ __forceinline__ void conv_seg(const int* __restrict__ spk_b,
                                         const int* seg, int tid,
                                         const float* __restrict__ Hpad,
                                         float* acc) {
    int jend = seg[G + 1];
    for (int j = seg[G]; j < jend; j++) {
        int tau = spk_b[j];
        int c = 512 + tid - tau;
        #pragma unroll
        for (int k = G; k < 8; k++) {
            acc[2 * k]     += Hpad[c + 512 * k];
            acc[2 * k + 1] += Hpad[c + 512 * k + 256];
        }
    }
}

__global__ __launch_bounds__(256, 8) void k_conv(const float* __restrict__ H,
                                                 const int* __restrict__ spk_idx,
                                                 const int* __restrict__ spk_cnt,
                                                 const float* __restrict__ g_m,
                                                 const float* __restrict__ b_m,
                                                 const float* __restrict__ mu_m,
                                                 const float* __restrict__ var_m,
                                                 float* __restrict__ m_bn) {
    __shared__ float Hpad[4608];                 // 512 zeros ++ H[ch,0..4096)
    __shared__ int seg[9];
    int bid = blockIdx.x;
    int b = bid >> 8, ch = bid & 255;
    int tid = threadIdx.x;

    float4* Hp4 = (float4*)Hpad;
    if (tid < 128) Hp4[tid] = make_float4(0.f, 0.f, 0.f, 0.f);
    const float4* Hv = (const float4*)(H + (size_t)ch * S_);
    for (int i = tid; i < 1024; i += 256) Hp4[128 + i] = Hv[i];

    int n = spk_cnt[b];
    const int* __restrict__ spk_b = spk_idx + (size_t)b * S_;
    if (tid < 8) {                               // seg[g] = first j with tau >= 512g
        int target = 512 * tid;
        int lo = 0, hi = n;
        while (lo < hi) {
            int mid = (lo + hi) >> 1;
            if (spk_b[mid] < target) lo = mid + 1; else hi = mid;
        }
        seg[tid] = lo;
    }
    if (tid == 8) seg[8] = n;
    __syncthreads();

    float acc[16];
    #pragma unroll
    for (int i = 0; i < 16; i++) acc[i] = 0.f;

    conv_seg<0>(spk_b, seg, tid, Hpad, acc);
    conv_seg<1>(spk_b, seg, tid, Hpad, acc);
    conv_seg<2>(spk_b, seg, tid, Hpad, acc);
    conv_seg<3>(spk_b, seg, tid, Hpad, acc);
    conv_seg<4>(spk_b, seg, tid, Hpad, acc);
    conv_seg<5>(spk_b, seg, tid, Hpad, acc);
    conv_seg<6>(spk_b, seg, tid, Hpad, acc);
    conv_seg<7>(spk_b, seg, tid, Hpad, acc);

    float g = g_m[ch], bb = b_m[ch], mu = mu_m[ch];
    float rs = 1.0f / sqrtf(var_m[ch] + EPS_);
    float* out = m_bn + ((size_t)b * M_ + ch) * S_;
    #pragma unroll
    for (int i = 0; i < 16; i++)
        out[tid + 256 * i] = g * (acc[i] - mu) * rs + bb;
}

// ---------------------------------------------------------------- K5: m-LIF (chunk 128, warm-up 128) -> m_s [B,S,M]
__global__ __launch_bounds__(256) void k_mlif(const float* __restrict__ m_bn,
                                              float* __restrict__ m_s) {
    int b = blockIdx.x;
    int ch = blockIdx.y * 64 + threadIdx.x;
    int c = blockIdx.z * 4 + threadIdx.y;        // 0..31
    int t0 = c * 128;
    int start = t0 - 128; if (start < 0) start = 0;
    const float* src = m_bn + ((size_t)b * M_ + ch) * S_;
    float v = 0.f;
    for (int t = start; t < t0 + 128; t += 4) {
        float4 xv = *(const float4*)(src + t);
        float xs[4] = {xv.x, xv.y, xv.z, xv.w};
        #pragma unroll
        for (int u = 0; u < 4; u++) {
            int t2 = t + u;
            v = v + (xs[u] - v) * 0.5f;
            float sp = (v - 1.0f) >= 0.0f ? 1.0f : 0.0f;
            if (t2 >= t0) m_s[((size_t)b * S_ + t2) * M_ + ch] = sp;
            v = v * (1.0f - sp);
        }
    }
}

// ---------------------------------------------------------------- K6: h GEMM (fp32) 128x128 tile, BK=16,
// 8x8/thread via 2x2 blocks of 4x4 fragments at offsets {0,+64}: all LDS
// fragment reads are float4 at 4-dword lane stride (<=2-way bank aliasing =
// free). LDS 16 KB -> high residency. Accumulation k-order identical to fp32
// reference path.
__global__ __launch_bounds__(256) void k_hgemm(const float* __restrict__ m_s,
                                               const float* __restrict__ x,
                                               const float* __restrict__ W,
                                               const float* __restrict__ Wb,
                                               const float* __restrict__ g_h,
                                               const float* __restrict__ b_h,
                                               const float* __restrict__ mu_h,
                                               const float* __restrict__ var_h,
                                               float* __restrict__ h_bn) {
    __shared__ float As[16 * 128];   // As[k][row]
    __shared__ float Bs[16 * 128];   // Bs[k][col]
    int tid = threadIdx.x;
    int row0 = blockIdx.x * 128, col0 = blockIdx.y * 128;
    int tx = tid & 15, ty = tid >> 4;          // ty 0..15
    int lrow = tid & 127, half = tid >> 7;     // staging
    float acc[2][2][4][4] = {};

    for (int kt = 0; kt < 24; kt++) {
        int kbase = kt * 16 + half * 8;
        const float* Asrc;
        if (kt < 16) Asrc = m_s + (size_t)(row0 + lrow) * M_ + kbase;
        else         Asrc = x   + (size_t)(row0 + lrow) * I_ + (kbase - M_);
        const float* Bsrc = W + (size_t)(col0 + lrow) * K_ + kbase;
        float4 va0 = *(const float4*)(Asrc);
        float4 va1 = *(const float4*)(Asrc + 4);
        float4 vb0 = *(const float4*)(Bsrc);
        float4 vb1 = *(const float4*)(Bsrc + 4);
        int k0 = half * 8;
        As[(k0 + 0) * 128 + lrow] = va0.x;
        As[(k0 + 1) * 128 + lrow] = va0.y;
        As[(k0 + 2) * 128 + lrow] = va0.z;
        As[(k0 + 3) * 128 + lrow] = va0.w;
        As[(k0 + 4) * 128 + lrow] = va1.x;
        As[(k0 + 5) * 128 + lrow] = va1.y;
        As[(k0 + 6) * 128 + lrow] = va1.z;
        As[(k0 + 7) * 128 + lrow] = va1.w;
        Bs[(k0 + 0) * 128 + lrow] = vb0.x;
        Bs[(k0 + 1) * 128 + lrow] = vb0.y;
        Bs[(k0 + 2) * 128 + lrow] = vb0.z;
        Bs[(k0 + 3) * 128 + lrow] = vb0.w;
        Bs[(k0 + 4) * 128 + lrow] = vb1.x;
        Bs[(k0 + 5) * 128 + lrow] = vb1.y;
        Bs[(k0 + 6) * 128 + lrow] = vb1.z;
        Bs[(k0 + 7) * 128 + lrow] = vb1.w;
        __syncthreads();
        #pragma unroll 4
        for (int kk = 0; kk < 16; kk++) {
            float4 a0 = *(const float4*)&As[kk * 128 + ty * 4];
            float4 a1 = *(const float4*)&As[kk * 128 + 64 + ty * 4];
            float4 b0 = *(const float4*)&Bs[kk * 128 + tx * 4];
            float4 b1 = *(const float4*)&Bs[kk * 128 + 64 + tx * 4];
            float av[2][4] = {{a0.x, a0.y, a0.z, a0.w}, {a1.x, a1.y, a1.z, a1.w}};
            float bv[2][4] = {{b0.x, b0.y, b0.z, b0.w}, {b1.x, b1.y, b1.z, b1.w}};
            #pragma unroll
            for (int ri = 0; ri < 2; ri++)
                #pragma unroll
                for (int ci = 0; ci < 2; ci++)
                    #pragma unroll
                    for (int r = 0; r < 4; r++)
                        #pragma unroll
                        for (int c = 0; c < 4; c++)
                            acc[ri][ci][r][c] += av[ri][r] * bv[ci][c];
        }
        __syncthreads();
    }

    #pragma unroll
    for (int ci = 0; ci < 2; ci++) {
        int col = col0 + ci * 64 + tx * 4;
        float4 g4  = *(const float4*)(g_h  + col);
        float4 b4  = *(const float4*)(b_h  + col);
        float4 mu4 = *(const float4*)(mu_h + col);
        float4 va4 = *(const float4*)(var_h + col);
        float4 wb4 = *(const float4*)(Wb   + col);
        float gg[4]  = {g4.x, g4.y, g4.z, g4.w};
        float bbv[4] = {b4.x, b4.y, b4.z, b4.w};
        float mm[4]  = {mu4.x, mu4.y, mu4.z, mu4.w};
        float wb[4]  = {wb4.x, wb4.y, wb4.z, wb4.w};
        float rs[4];
        rs[0] = 1.0f / sqrtf(va4.x + EPS_);
        rs[1] = 1.0f / sqrtf(va4.y + EPS_);
        rs[2] = 1.0f / sqrtf(va4.z + EPS_);
        rs[3] = 1.0f / sqrtf(va4.w + EPS_);
        #pragma unroll
        for (int ri = 0; ri < 2; ri++) {
            #pragma unroll
            for (int r = 0; r < 4; r++) {
                int row = row0 + ri * 64 + ty * 4 + r;
                float o[4];
                #pragma unroll
                for (int c = 0; c < 4; c++)
                    o[c] = gg[c] * ((acc[ri][ci][r][c] + wb[c]) - mm[c]) * rs[c] + bbv[c];
                float4 o4 = {o[0], o[1], o[2], o[3]};
                *(float4*)(h_bn + (size_t)row * HD_ + col) = o4;
            }
        }
    }
}

// ---------------------------------------------------------------- K7: h-LIF (chunk 128, warm-up 128) -> out
__global__ __launch_bounds__(256) void k_hlif(const float* __restrict__ h_bn,
                                              float* __restrict__ out) {
    int b = blockIdx.x;
    int j = blockIdx.y * 64 + threadIdx.x;
    int c = blockIdx.z * 4 + threadIdx.y;        // 0..31
    int t0 = c * 128;
    int start = t0 - 128; if (start < 0) start = 0;
    float* hn = out + (size_t)B_ * S_ * HD_;
    float v = 0.f;
    for (int t = start; t < t0 + 128; t++) {
        float xv = h_bn[((size_t)b * S_ + t) * HD_ + j];
        v = v + (xv - v) * 0.5f;
        float sp = (v - 1.0f) >= 0.0f ? 1.0f : 0.0f;
        if (t >= t0) {
            out[((size_t)b * S_ + t) * HD_ + j] = sp;
            if (t == S_ - 1) hn[(size_t)b * HD_ + j] = sp;
        }
        v = v * (1.0f - sp);
    }
}

// ---------------------------------------------------------------- launch
extern "C" void kernel_launch(void* const* d_in, const int* in_sizes, int n_in,
                              void* d_out, int out_size, void* d_ws, size_t ws_size,
                              hipStream_t stream) {
    const float* x     = (const float*)d_in[0];
    const float* H     = (const float*)d_in[1];
    const float* Wu    = (const float*)d_in[2];
    const float* Wub   = (const float*)d_in[3];
    const float* Wh    = (const float*)d_in[4];
    const float* Whb   = (const float*)d_in[5];
    const float* g_u   = (const float*)d_in[6];
    const float* b_u   = (const float*)d_in[7];
    const float* mu_u  = (const float*)d_in[8];
    const float* var_u = (const float*)d_in[9];
    const float* g_m   = (const float*)d_in[10];
    const float* b_m   = (const float*)d_in[11];
    const float* mu_m  = (const float*)d_in[12];
    const float* var_m = (const float*)d_in[13];
    const float* g_h   = (const float*)d_in[14];
    const float* b_h   = (const float*)d_in[15];
    const float* mu_h  = (const float*)d_in[16];
    const float* var_h = (const float*)d_in[17];

    float* ws    = (float*)d_ws;
    float* u_bn  = ws;                               // 65536
    float* u_spk = ws + 65536;                       // 65536
    int*   spk_idx = (int*)(ws + 131072);            // 65536 ints
    int*   spk_cnt = (int*)(ws + 196608);            // 16 ints
    float* m_bn  = ws + 200704;                      // 16777216  [B,M,S]
    float* m_s   = m_bn + 16777216;                  // 16777216  [B,S,M]
    float* h_bn  = m_s + 16777216;                   // 25165824  [B*S,HD]

    k_upre<<<dim3(256), dim3(256), 0, stream>>>(x, Wu, Wub, g_u, b_u, mu_u, var_u, u_bn);
    k_ulif<<<dim3(16, 4), dim3(256), 0, stream>>>(u_bn, u_spk);
    k_compact<<<dim3(16), dim3(256), 0, stream>>>(u_spk, spk_idx, spk_cnt);
    k_conv<<<dim3(4096), dim3(256), 0, stream>>>(H, spk_idx, spk_cnt,
                                                 g_m, b_m, mu_m, var_m, m_bn);
    k_mlif<<<dim3(16, 4, 8), dim3(64, 4), 0, stream>>>(m_bn, m_s);
    k_hgemm<<<dim3(512, 3), dim3(256), 0, stream>>>(m_s, x, Wh, Whb,
                                                    g_h, b_h, mu_h, var_h, h_bn);
    k_hlif<<<dim3(16, 6, 8), dim3(64, 4), 0, stream>>>(h_bn, (float*)d_out);
}

// Round 9
// 614.640 us; speedup vs baseline: 1.1679x; 1.1679x over previous
//
#include <hip/hip_runtime.h>
#include <math.h>

#define B_   16
#define S_   4096
#define I_   128
#define HD_  384
#define M_   256
#define K_   384   // M_+I_
#define EPS_ 1e-5f

typedef __attribute__((ext_vector_type(8))) short short8;
typedef __attribute__((ext_vector_type(4))) float floatx4;

__device__ __forceinline__ unsigned short f2b(float f) {   // fp32 -> bf16 RNE bits
    unsigned int u = __float_as_uint(f);
    u += 0x7FFF + ((u >> 16) & 1);
    return (unsigned short)(u >> 16);
}
__device__ __forceinline__ float b2f(unsigned short b) {
    return __uint_as_float(((unsigned int)b) << 16);
}

// ---------------------------------------------------------------- K1: u_pre + BN(u)
__global__ __launch_bounds__(256) void k_upre(const float* __restrict__ x,
                                              const float* __restrict__ wu,
                                              const float* __restrict__ wub,
                                              const float* __restrict__ g_u,
                                              const float* __restrict__ b_u,
                                              const float* __restrict__ mu_u,
                                              const float* __restrict__ var_u,
                                              float* __restrict__ u_bn) {
    __shared__ float w[I_];
    int tid = threadIdx.x;
    if (tid < I_) w[tid] = wu[tid];
    __syncthreads();
    int row = blockIdx.x * 256 + tid;
    const float4* xr = (const float4*)(x + (size_t)row * I_);
    const float4* w4 = (const float4*)w;
    float4 s4 = {0.f, 0.f, 0.f, 0.f};
    #pragma unroll
    for (int i = 0; i < I_ / 4; i++) {
        float4 xv = xr[i], wv = w4[i];
        s4.x += xv.x * wv.x; s4.y += xv.y * wv.y;
        s4.z += xv.z * wv.z; s4.w += xv.w * wv.w;
    }
    float s = (s4.x + s4.y) + (s4.z + s4.w) + wub[0];
    float rs = 1.0f / sqrtf(var_u[0] + EPS_);
    u_bn[row] = g_u[0] * (s - mu_u[0]) * rs + b_u[0];
}

// ---------------------------------------------------------------- K2: u-LIF (chunk 4, warm-up 128)
__global__ __launch_bounds__(256) void k_ulif(const float* __restrict__ u_bn,
                                              float* __restrict__ u_spk) {
    int b = blockIdx.x, tid = threadIdx.x;
    int chunk = blockIdx.y * 256 + tid;
    int t0 = chunk * 4;
    int start = t0 - 128; if (start < 0) start = 0;
    const float* ub = u_bn + (size_t)b * S_;
    float v = 0.f;
    for (int t = start; t < t0 + 4; t++) {
        float xv = ub[t];
        v = v + (xv - v) * 0.5f;
        float sp = (v - 1.0f) >= 0.0f ? 1.0f : 0.0f;
        if (t >= t0) u_spk[(size_t)b * S_ + t] = sp;
        v = v * (1.0f - sp);
    }
}

// ---------------------------------------------------------------- K2b: compact sorted spike lists
__global__ __launch_bounds__(256) void k_compact(const float* __restrict__ u_spk,
                                                 int* __restrict__ spk_idx,
                                                 int* __restrict__ spk_cnt) {
    __shared__ int wcnt[4];
    __shared__ int base;
    int b = blockIdx.x, tid = threadIdx.x;
    int lane = tid & 63, w = tid >> 6;
    if (tid == 0) base = 0;
    __syncthreads();
    for (int r = 0; r < 16; r++) {
        int t = r * 256 + tid;
        bool f = u_spk[(size_t)b * S_ + t] > 0.5f;
        unsigned long long bal = __ballot(f);
        int pre = __popcll(bal & (((unsigned long long)1 << lane) - 1ull));
        if (lane == 0) wcnt[w] = __popcll(bal);
        __syncthreads();
        int off = base;
        for (int i = 0; i < w; i++) off += wcnt[i];
        if (f) spk_idx[(size_t)b * S_ + off + pre] = t;
        __syncthreads();
        if (tid == 0) base += wcnt[0] + wcnt[1] + wcnt[2] + wcnt[3];
        __syncthreads();
    }
    if (tid == 0) spk_cnt[b] = base;
}

// ---------------------------------------------------------------- K3: sparse conv + BN(m) -> m_bn [B,M,S]  (unchanged r6)
template<int G>
__device__ __forceinline__ void conv_seg(const int* __restrict__ spk_b,
                                         const int* seg, int tid,
                                         const float* __restrict__ Hpad,
                                         float* acc) {
    int jend = seg[G + 1];
    for (int j = seg[G]; j < jend; j++) {
        int tau = spk_b[j];
        int c = 512 + tid - tau;
        #pragma unroll
        for (int k = G; k < 8; k++) {
            acc[2 * k]     += Hpad[c + 512 * k];
            acc[2 * k + 1] += Hpad[c + 512 * k + 256];
        }
    }
}

__global__ __launch_bounds__(256, 8) void k_conv(const float* __restrict__ H,
                                                 const int* __restrict__ spk_idx,
                                                 const int* __restrict__ spk_cnt,
                                                 const float* __restrict__ g_m,
                                                 const float* __restrict__ b_m,
                                                 const float* __restrict__ mu_m,
                                                 const float* __restrict__ var_m,
                                                 float* __restrict__ m_bn) {
    __shared__ float Hpad[4608];
    __shared__ int seg[9];
    int bid = blockIdx.x;
    int b = bid >> 8, ch = bid & 255;
    int tid = threadIdx.x;

    float4* Hp4 = (float4*)Hpad;
    if (tid < 128) Hp4[tid] = make_float4(0.f, 0.f, 0.f, 0.f);
    const float4* Hv = (const float4*)(H + (size_t)ch * S_);
    for (int i = tid; i < 1024; i += 256) Hp4[128 + i] = Hv[i];

    int n = spk_cnt[b];
    const int* __restrict__ spk_b = spk_idx + (size_t)b * S_;
    if (tid < 8) {
        int target = 512 * tid;
        int lo = 0, hi = n;
        while (lo < hi) {
            int mid = (lo + hi) >> 1;
            if (spk_b[mid] < target) lo = mid + 1; else hi = mid;
        }
        seg[tid] = lo;
    }
    if (tid == 8) seg[8] = n;
    __syncthreads();

    float acc[16];
    #pragma unroll
    for (int i = 0; i < 16; i++) acc[i] = 0.f;

    conv_seg<0>(spk_b, seg, tid, Hpad, acc);
    conv_seg<1>(spk_b, seg, tid, Hpad, acc);
    conv_seg<2>(spk_b, seg, tid, Hpad, acc);
    conv_seg<3>(spk_b, seg, tid, Hpad, acc);
    conv_seg<4>(spk_b, seg, tid, Hpad, acc);
    conv_seg<5>(spk_b, seg, tid, Hpad, acc);
    conv_seg<6>(spk_b, seg, tid, Hpad, acc);
    conv_seg<7>(spk_b, seg, tid, Hpad, acc);

    float g = g_m[ch], bb = b_m[ch], mu = mu_m[ch];
    float rs = 1.0f / sqrtf(var_m[ch] + EPS_);
    float* out = m_bn + ((size_t)b * M_ + ch) * S_;
    #pragma unroll
    for (int i = 0; i < 16; i++)
        out[tid + 256 * i] = g * (acc[i] - mu) * rs + bb;
}

// ---------------------------------------------------------------- K5: m-LIF -> m_s as bf16 bits [B,S,M]
__global__ __launch_bounds__(256) void k_mlif(const float* __restrict__ m_bn,
                                              unsigned short* __restrict__ msb) {
    int b = blockIdx.x;
    int ch = blockIdx.y * 64 + threadIdx.x;
    int c = blockIdx.z * 4 + threadIdx.y;        // 0..31
    int t0 = c * 128;
    int start = t0 - 128; if (start < 0) start = 0;
    const float* src = m_bn + ((size_t)b * M_ + ch) * S_;
    float v = 0.f;
    for (int t = start; t < t0 + 128; t += 4) {
        float4 xv = *(const float4*)(src + t);
        float xs[4] = {xv.x, xv.y, xv.z, xv.w};
        #pragma unroll
        for (int u = 0; u < 4; u++) {
            int t2 = t + u;
            v = v + (xs[u] - v) * 0.5f;
            float sp = (v - 1.0f) >= 0.0f ? 1.0f : 0.0f;
            if (t2 >= t0)
                msb[((size_t)b * S_ + t2) * M_ + ch] = (sp > 0.5f) ? 0x3F80 : 0;
            v = v * (1.0f - sp);
        }
    }
}

// ---------------------------------------------------------------- K5b: x -> bf16 3-way split (hi/lo/lo2)
__global__ __launch_bounds__(256) void k_xprep(const float* __restrict__ x,
                                               unsigned int* __restrict__ xhi,
                                               unsigned int* __restrict__ xlo,
                                               unsigned int* __restrict__ xlo2) {
    int t = blockIdx.x * 256 + threadIdx.x;      // 0 .. 2097151, 4 floats each
    float4 v = *(const float4*)(x + (size_t)t * 4);
    float f[4] = {v.x, v.y, v.z, v.w};
    unsigned int h[4], l[4], l2[4];
    #pragma unroll
    for (int i = 0; i < 4; i++) {
        unsigned short hb = f2b(f[i]);
        float r1 = f[i] - b2f(hb);
        unsigned short lb = f2b(r1);
        float r2 = r1 - b2f(lb);
        h[i] = hb; l[i] = lb; l2[i] = f2b(r2);
    }
    xhi[2 * t]      = h[0] | (h[1] << 16);
    xhi[2 * t + 1]  = h[2] | (h[3] << 16);
    xlo[2 * t]      = l[0] | (l[1] << 16);
    xlo[2 * t + 1]  = l[2] | (l[3] << 16);
    xlo2[2 * t]     = l2[0] | (l2[1] << 16);
    xlo2[2 * t + 1] = l2[2] | (l2[3] << 16);
}

// ---------------------------------------------------------------- K5c: W_h -> packed split W_all [384, 1536] bf16
// cols: [0,256) Wm_hi | [256,512) Wm_lo | [512,768) Wm_lo2 |
//       [768,896) Wx_hi | [896,1024) Wx_lo | [1024,1152) Wx_lo2 |
//       [1152,1280) Wx_hi | [1280,1408) Wx_lo | [1408,1536) Wx_hi
__global__ __launch_bounds__(256) void k_wprep(const float* __restrict__ Wh,
                                               unsigned short* __restrict__ Wall) {
    int c = blockIdx.x;                          // 0..383
    for (int kk = threadIdx.x; kk < 1536; kk += 256) {
        int k; int part;                         // 0=hi 1=lo 2=lo2
        if (kk < 256)       { k = kk;              part = 0; }
        else if (kk < 512)  { k = kk - 256;        part = 1; }
        else if (kk < 768)  { k = kk - 512;        part = 2; }
        else if (kk < 896)  { k = 256 + kk - 768;  part = 0; }
        else if (kk < 1024) { k = 256 + kk - 896;  part = 1; }
        else if (kk < 1152) { k = 256 + kk - 1024; part = 2; }
        else if (kk < 1280) { k = 256 + kk - 1152; part = 0; }
        else if (kk < 1408) { k = 256 + kk - 1280; part = 1; }
        else                { k = 256 + kk - 1408; part = 0; }
        float w = Wh[(size_t)c * K_ + k];
        unsigned short hb = f2b(w);
        unsigned short out = hb;
        if (part >= 1) {
            float r1 = w - b2f(hb);
            unsigned short lb = f2b(r1);
            out = lb;
            if (part == 2) out = f2b(r1 - b2f(lb));
        }
        Wall[(size_t)c * 1536 + kk] = out;
    }
}

// ---------------------------------------------------------------- K6: h GEMM via bf16 MFMA (split-exact), 128x128 tile
// Virtual K = 1536 (48 x BK=32):
//   kt 0-23 : A = msb (x3 for Wm_hi/lo/lo2)
//   kt 24-35: A = xhi  (Wx_hi, Wx_lo, Wx_lo2)
//   kt 36-43: A = xlo  (Wx_hi, Wx_lo)
//   kt 44-47: A = xlo2 (Wx_hi)
// Dropped terms are O(2^-27) relative -- below fp32 reorder noise.
__global__ __launch_bounds__(256) void k_hgemm(const unsigned short* __restrict__ msb,
                                               const unsigned short* __restrict__ xhi,
                                               const unsigned short* __restrict__ xlo,
                                               const unsigned short* __restrict__ xlo2,
                                               const unsigned short* __restrict__ Wall,
                                               const float* __restrict__ Wb,
                                               const float* __restrict__ g_h,
                                               const float* __restrict__ b_h,
                                               const float* __restrict__ mu_h,
                                               const float* __restrict__ var_h,
                                               float* __restrict__ h_bn) {
    __shared__ unsigned short As[128 * 32];
    __shared__ unsigned short Bs[128 * 32];
    int tid = threadIdx.x;
    int row0 = blockIdx.x * 128, col0 = blockIdx.y * 128;
    int ln = tid & 63, wv = tid >> 6;
    int wm = wv >> 1, wn = wv & 1;
    int colq = ln & 15, quad = ln >> 4;
    int srow = ln >> 2, sbyte = (ln & 3) * 16;

    floatx4 acc[4][4];
    #pragma unroll
    for (int i = 0; i < 4; i++)
        #pragma unroll
        for (int j = 0; j < 4; j++)
            acc[i][j] = (floatx4){0.f, 0.f, 0.f, 0.f};

    for (int kt = 0; kt < 48; kt++) {
        const char* abase; int astride, aoff;
        if (kt < 24) {
            abase = (const char*)msb; astride = 512; aoff = (kt & 7) * 64;
        } else {
            int p = (kt - 24) >> 2;
            abase = (p < 3) ? (const char*)xhi : (p < 5) ? (const char*)xlo
                                               : (const char*)xlo2;
            astride = 256; aoff = ((kt - 24) & 3) * 64;
        }
        int boff = kt * 64;
        #pragma unroll
        for (int q = 0; q < 2; q++) {
            int r16 = wv * 32 + q * 16;
            uint4 va = *(const uint4*)(abase + (size_t)(row0 + r16 + srow) * astride + aoff + sbyte);
            uint4 vb = *(const uint4*)((const char*)Wall + (size_t)(col0 + r16 + srow) * 3072 + boff + sbyte);
            *(uint4*)((char*)As + r16 * 64 + ln * 16) = va;
            *(uint4*)((char*)Bs + r16 * 64 + ln * 16) = vb;
        }
        __syncthreads();
        short8 a[4], b[4];
        #pragma unroll
        for (int i = 0; i < 4; i++)
            a[i] = *(const short8*)((const char*)As + (wm * 64 + i * 16 + colq) * 64 + quad * 16);
        #pragma unroll
        for (int j = 0; j < 4; j++)
            b[j] = *(const short8*)((const char*)Bs + (wn * 64 + j * 16 + colq) * 64 + quad * 16);
        #pragma unroll
        for (int i = 0; i < 4; i++)
            #pragma unroll
            for (int j = 0; j < 4; j++)
                acc[i][j] = __builtin_amdgcn_mfma_f32_16x16x32_bf16(a[i], b[j], acc[i][j], 0, 0, 0);
        __syncthreads();
    }

    #pragma unroll
    for (int j = 0; j < 4; j++) {
        int col = col0 + wn * 64 + j * 16 + colq;
        float gj = g_h[col], bj = b_h[col], mj = mu_h[col];
        float wj = Wb[col];
        float rsj = 1.0f / sqrtf(var_h[col] + EPS_);
        #pragma unroll
        for (int i = 0; i < 4; i++) {
            int rowb = row0 + wm * 64 + i * 16 + quad * 4;
            #pragma unroll
            for (int r = 0; r < 4; r++) {
                float o = gj * ((acc[i][j][r] + wj) - mj) * rsj + bj;
                h_bn[(size_t)(rowb + r) * HD_ + col] = o;
            }
        }
    }
}

// ---------------------------------------------------------------- K7: h-LIF (chunk 128, warm-up 128) -> out
__global__ __launch_bounds__(256) void k_hlif(const float* __restrict__ h_bn,
                                              float* __restrict__ out) {
    int b = blockIdx.x;
    int j = blockIdx.y * 64 + threadIdx.x;
    int c = blockIdx.z * 4 + threadIdx.y;        // 0..31
    int t0 = c * 128;
    int start = t0 - 128; if (start < 0) start = 0;
    float* hn = out + (size_t)B_ * S_ * HD_;
    float v = 0.f;
    for (int t = start; t < t0 + 128; t++) {
        float xv = h_bn[((size_t)b * S_ + t) * HD_ + j];
        v = v + (xv - v) * 0.5f;
        float sp = (v - 1.0f) >= 0.0f ? 1.0f : 0.0f;
        if (t >= t0) {
            out[((size_t)b * S_ + t) * HD_ + j] = sp;
            if (t == S_ - 1) hn[(size_t)b * HD_ + j] = sp;
        }
        v = v * (1.0f - sp);
    }
}

// ---------------------------------------------------------------- launch
extern "C" void kernel_launch(void* const* d_in, const int* in_sizes, int n_in,
                              void* d_out, int out_size, void* d_ws, size_t ws_size,
                              hipStream_t stream) {
    const float* x     = (const float*)d_in[0];
    const float* H     = (const float*)d_in[1];
    const float* Wu    = (const float*)d_in[2];
    const float* Wub   = (const float*)d_in[3];
    const float* Wh    = (const float*)d_in[4];
    const float* Whb   = (const float*)d_in[5];
    const float* g_u   = (const float*)d_in[6];
    const float* b_u   = (const float*)d_in[7];
    const float* mu_u  = (const float*)d_in[8];
    const float* var_u = (const float*)d_in[9];
    const float* g_m   = (const float*)d_in[10];
    const float* b_m   = (const float*)d_in[11];
    const float* mu_m  = (const float*)d_in[12];
    const float* var_m = (const float*)d_in[13];
    const float* g_h   = (const float*)d_in[14];
    const float* b_h   = (const float*)d_in[15];
    const float* mu_h  = (const float*)d_in[16];
    const float* var_h = (const float*)d_in[17];

    float* ws = (float*)d_ws;
    // layout (floats). xhi/xlo/xlo2 overlay m_bn (dead after k_mlif); Wall fresh.
    float* u_bn    = ws;                                       // [0, 65536)
    float* u_spk   = ws + 65536;                               // [65536, 131072)
    int*   spk_idx = (int*)(ws + 131072);                      // [131072, 196608)
    int*   spk_cnt = (int*)(ws + 196608);
    float* m_bn    = ws + 200704;                              // [200704, 16977920)
    unsigned int* xhi_u  = (unsigned int*)(ws + 200704);       // 4194304 floats
    unsigned int* xlo_u  = (unsigned int*)(ws + 4395008);      // 4194304 floats
    unsigned int* xlo2_u = (unsigned int*)(ws + 8589312);      // 4194304 floats
    float* h_bn    = ws + 16977920;                            // [16977920, 42143744)
    unsigned short* msb  = (unsigned short*)(ws + 42143744);   // 8388608 floats
    unsigned short* Wall = (unsigned short*)(ws + 50532352);   // 294912 floats -> 50827264

    k_upre<<<dim3(256), dim3(256), 0, stream>>>(x, Wu, Wub, g_u, b_u, mu_u, var_u, u_bn);
    k_ulif<<<dim3(16, 4), dim3(256), 0, stream>>>(u_bn, u_spk);
    k_compact<<<dim3(16), dim3(256), 0, stream>>>(u_spk, spk_idx, spk_cnt);
    k_conv<<<dim3(4096), dim3(256), 0, stream>>>(H, spk_idx, spk_cnt,
                                                 g_m, b_m, mu_m, var_m, m_bn);
    k_mlif<<<dim3(16, 4, 8), dim3(64, 4), 0, stream>>>(m_bn, msb);
    k_xprep<<<dim3(8192), dim3(256), 0, stream>>>(x, xhi_u, xlo_u, xlo2_u);
    k_wprep<<<dim3(384), dim3(256), 0, stream>>>(Wh, Wall);
    k_hgemm<<<dim3(512, 3), dim3(256), 0, stream>>>(msb,
                                                    (const unsigned short*)xhi_u,
                                                    (const unsigned short*)xlo_u,
                                                    (const unsigned short*)xlo2_u,
                                                    Wall, Whb, g_h, b_h, mu_h, var_h, h_bn);
    k_hlif<<<dim3(16, 6, 8), dim3(64, 4), 0, stream>>>(h_bn, (float*)d_out);
}